// Round 2
// baseline (407.241 us; speedup 1.0000x reference)
//
#include <hip/hip_runtime.h>

#define NN 4096
#define DD 256
#define EE 131072

typedef __attribute__((ext_vector_type(8))) short s16x8;
typedef __attribute__((ext_vector_type(4))) float f32x4;

__device__ __forceinline__ unsigned short f2bf(float f) {
  unsigned u = __builtin_bit_cast(unsigned, f);
  u += 0x7FFFu + ((u >> 16) & 1u);
  return (unsigned short)(u >> 16);
}

__device__ __forceinline__ ushort4 cvt4(f32x4 v) {
  ushort4 r;
  r.x = f2bf(v[0]); r.y = f2bf(v[1]); r.z = f2bf(v[2]); r.w = f2bf(v[3]);
  return r;
}

// round-half-up fp32->bf16 pair pack: 2 adds + 1 v_perm
__device__ __forceinline__ unsigned cvt2_rhu(float a, float b) {
  unsigned ua = __builtin_bit_cast(unsigned, a) + 0x8000u;
  unsigned ub = __builtin_bit_cast(unsigned, b) + 0x8000u;
  return __builtin_amdgcn_perm(ub, ua, 0x07060302u);
}

__device__ __forceinline__ uint4 pack8(f32x4 a, f32x4 b) {
  uint4 r;
  r.x = cvt2_rhu(a[0], a[1]); r.y = cvt2_rhu(a[2], a[3]);
  r.z = cvt2_rhu(b[0], b[1]); r.w = cvt2_rhu(b[2], b[3]);
  return r;
}

__device__ __forceinline__ s16x8 pack8f(f32x4 a, f32x4 b) {
  uint4 p = pack8(a, b);
  return __builtin_bit_cast(s16x8, p);
}

// B fragment layout (consumed by mfma_16x16x32_bf16 B-operand):
//   element (n, k) of a 256-col operand lives at ushort index
//   (tile*128 + kc)*512 + (quad*16 + (n&15))*8 + (k&7)
//   tile = n>>4, kc = k>>5, quad = (k>>3)&3.  One wave chunk-load = 1KB coalesced.

// ---------------------------------------------------------------------------
// K1: count in-degrees + write both W matrices in B-fragment layout (bf16)
// ---------------------------------------------------------------------------
__global__ void k_prep(const int* __restrict__ ei, int* __restrict__ deg,
                       const float* __restrict__ Wh, const float* __restrict__ Wc,
                       unsigned short* __restrict__ WFh, unsigned short* __restrict__ WFc) {
  int t = blockIdx.x * 256 + threadIdx.x;
  if (t < EE) {
    atomicAdd(&deg[ei[EE + t]], 1);
  } else {
    int idx = t - EE;                 // 0..131071
    int which = idx >> 16;            // 0: W_high, 1: W_conv
    int r = idx & 65535;
    int n = r & 255, k = r >> 8;      // consecutive threads -> consecutive n (coalesced read)
    const float* W = which ? Wc : Wh;
    unsigned short* WF = which ? WFc : WFh;
    long fidx = ((long)((n >> 4) * 8 + (k >> 5))) * 512 +
                (((k >> 3) & 3) * 16 + (n & 15)) * 8 + (k & 7);
    WF[fidx] = f2bf(W[k * 256 + n]);  // fragment(n,k) = W[k][n]
  }
}

// ---------------------------------------------------------------------------
// K2: exclusive scan of deg -> row_start[4097]; dis = rsqrt(deg+1)
// ---------------------------------------------------------------------------
__global__ void k_scan(const int* __restrict__ deg, int* __restrict__ row_start,
                       float* __restrict__ dis) {
  __shared__ int part[1024];
  int t = threadIdx.x;
  int d0 = deg[4 * t + 0], d1 = deg[4 * t + 1], d2 = deg[4 * t + 2], d3 = deg[4 * t + 3];
  int s = d0 + d1 + d2 + d3;
  part[t] = s;
  __syncthreads();
  for (int off = 1; off < 1024; off <<= 1) {
    int add = (t >= off) ? part[t - off] : 0;
    __syncthreads();
    part[t] += add;
    __syncthreads();
  }
  int base = part[t] - s;
  row_start[4 * t + 0] = base;
  row_start[4 * t + 1] = base + d0;
  row_start[4 * t + 2] = base + d0 + d1;
  row_start[4 * t + 3] = base + d0 + d1 + d2;
  if (t == 1023) row_start[4096] = part[t];
  dis[4 * t + 0] = rsqrtf((float)d0 + 1.0f);
  dis[4 * t + 1] = rsqrtf((float)d1 + 1.0f);
  dis[4 * t + 2] = rsqrtf((float)d2 + 1.0f);
  dis[4 * t + 3] = rsqrtf((float)d3 + 1.0f);
}

// ---------------------------------------------------------------------------
// K3: scatter edges into CSR buckets
// ---------------------------------------------------------------------------
__global__ void k_scatter(const int* __restrict__ ei, const int* __restrict__ row_start,
                          int* __restrict__ cursor, int* __restrict__ csr) {
  int e = blockIdx.x * 256 + threadIdx.x;
  if (e < EE) {
    int s = ei[e];
    int d = ei[EE + e];
    int p = atomicAdd(&cursor[d], 1);
    csr[row_start[d] + p] = s;
  }
}

// ---------------------------------------------------------------------------
// K4: RF = frag(relu(x @ W_high))  and  XWs[m][n] = dis[m] * (x @ W_conv)[m][n]
//     grid 256 (16-row M-tiles), block 512. waves 0-3: high, 4-7: conv.
//     All B loads are coalesced 1KB fragment loads.
// ---------------------------------------------------------------------------
__global__ __launch_bounds__(512) void k_xw(const float* __restrict__ x,
                                            const unsigned short* __restrict__ WFh,
                                            const unsigned short* __restrict__ WFc,
                                            unsigned short* __restrict__ RF,
                                            float* __restrict__ XWs,
                                            const float* __restrict__ dis) {
  __shared__ alignas(16) unsigned short Abuf[16][264];
  const int tid = threadIdx.x;
  const int w = tid >> 6, lane = tid & 63;
  const int quad = lane >> 4, l16 = lane & 15, quad8 = quad * 8;
  const int m0 = blockIdx.x * 16;

  {
    int srow = tid >> 5, scolf = (tid & 31) * 8;
    const float* ap = x + (long)(m0 + srow) * DD + scolf;
    f32x4 a0 = *(const f32x4*)ap;
    f32x4 a1 = *(const f32x4*)(ap + 4);
    *(uint4*)&Abuf[srow][scolf] = pack8(a0, a1);
  }
  __syncthreads();

  const bool hi = (w < 4);
  const int wo = hi ? w : (w - 4);
  const unsigned short* WF = hi ? WFh : WFc;
  const unsigned short* bp = WF + lane * 8;

  f32x4 acc[4] = {{0,0,0,0},{0,0,0,0},{0,0,0,0},{0,0,0,0}};
#pragma unroll
  for (int q = 0; q < 8; ++q) {
    s16x8 af = *(const s16x8*)&Abuf[l16][q * 32 + quad8];
#pragma unroll
    for (int s = 0; s < 4; ++s) {
      s16x8 bf = *(const s16x8*)(bp + ((long)((4 * wo + s) * 8 + q)) * 512);
      acc[s] = __builtin_amdgcn_mfma_f32_16x16x32_bf16(af, bf, acc[s], 0, 0, 0);
    }
  }

  if (hi) {
    const int kc = m0 >> 5;
    const int qp = ((m0 >> 4) & 1) * 2 + (quad >> 1);
    const int j0 = (quad & 1) * 4;
#pragma unroll
    for (int s = 0; s < 4; ++s) {
      int t = 4 * wo + s;
      f32x4 v = acc[s];
      f32x4 z;
      z[0] = v[0] > 0.f ? v[0] : 0.f;
      z[1] = v[1] > 0.f ? v[1] : 0.f;
      z[2] = v[2] > 0.f ? v[2] : 0.f;
      z[3] = v[3] > 0.f ? v[3] : 0.f;
      long idx = ((long)(t * 128 + kc)) * 512 + (qp * 16 + l16) * 8 + j0;
      *(ushort4*)(RF + idx) = cvt4(z);
    }
  } else {
    float dm[4];
#pragma unroll
    for (int r = 0; r < 4; ++r) dm[r] = dis[m0 + quad * 4 + r];
#pragma unroll
    for (int s = 0; s < 4; ++s) {
      int col = 64 * wo + 16 * s + l16;
#pragma unroll
      for (int r = 0; r < 4; ++r)
        XWs[(long)(m0 + quad * 4 + r) * DD + col] = dm[r] * acc[s][r];
    }
  }
}

// ---------------------------------------------------------------------------
// K5: GCN aggregation, dis pre-multiplied into XWs; unroll-by-4 gathers
// ---------------------------------------------------------------------------
__global__ void k_agg(const float* __restrict__ XWs, const int* __restrict__ row_start,
                      const int* __restrict__ csr, const float* __restrict__ dis,
                      float* __restrict__ Hl) {
  const int i = blockIdx.x;
  const int t = threadIdx.x;
  const int b0 = row_start[i], b1 = row_start[i + 1];
  float acc = XWs[(long)i * DD + t];   // self loop
  int j = b0;
  for (; j + 4 <= b1; j += 4) {
    int s0 = csr[j], s1 = csr[j + 1], s2 = csr[j + 2], s3 = csr[j + 3];
    float v0 = XWs[(long)s0 * DD + t];
    float v1 = XWs[(long)s1 * DD + t];
    float v2 = XWs[(long)s2 * DD + t];
    float v3 = XWs[(long)s3 * DD + t];
    acc += (v0 + v1) + (v2 + v3);
  }
  for (; j < b1; ++j) acc += XWs[(long)csr[j] * DD + t];
  Hl[(long)i * DD + t] = dis[i] * acc;
}

// ---------------------------------------------------------------------------
// K6: C[4096 x 256] = A[4096 x 4096](fp32) @ B, B in fragment layout (bf16).
//     BARRIER-FREE register streaming: no LDS, no __syncthreads in the K-loop.
//     Round-1 evidence: lockstep barrier + vmcnt(0) drain pinned the kernel at
//     ~1.4 TB/s regardless of occupancy. Here every wave streams independently:
//     A fp32 global->reg (16-row x 128B fragment gather, lines fully consumed),
//     in-reg fp32->bf16 pack, B fragments from L2-resident BF.
//     grid 256 = 128 m-blocks (32 rows) x 2 n-halves; pair (b, b+128) shares
//     the A panel and lands on the same XCD (128 % 8 == 0).
//     Block 512 = 8 waves: wave w -> msub = w&1 (16 rows), nsub = w>>1
//     (tiles t0 = nhalf*8 + nsub*2, t0+1). The 4 waves per msub read identical
//     A addresses -> L1 broadcast.
//     Register pipeline: 2 buffers x 4 k-chunks (16 loads = 16KB/wave in
//     flight), compiler counted-vmcnt keeps the HBM stream saturated.
//     EPI 0: write C in fragment layout (next mm's B).  EPI 3: fused final.
// ---------------------------------------------------------------------------
template <int EPI>
__global__ __launch_bounds__(512) void k_mm2(const float* __restrict__ A,
                                             const unsigned short* __restrict__ BF,
                                             unsigned short* __restrict__ CF,
                                             float* __restrict__ outF,
                                             const float* __restrict__ Hl,
                                             const float* __restrict__ bconv,
                                             const float* __restrict__ aLp,
                                             const float* __restrict__ aHp) {
  const int tid = threadIdx.x;
  const int w = tid >> 6, lane = tid & 63;
  const int quad = lane >> 4, l16 = lane & 15;
  const int mblk = blockIdx.x & 127, nhalf = blockIdx.x >> 7;
  const int msub = w & 1, nsub = w >> 1;
  const int mrow = mblk * 32 + msub * 16 + l16;    // A row this lane reads
  const int t0 = nhalf * 8 + nsub * 2;             // first n-tile of this wave

  const float* ap = A + (long)mrow * NN + quad * 8;
  const unsigned short* bp0 = BF + ((long)t0 * 128) * 512 + lane * 8;
  const unsigned short* bp1 = bp0 + 128l * 512;

  // double-buffered register pipeline: X holds even groups, Y odd groups;
  // each group = 4 k-chunks of 32.
  f32x4 xa0[4], xa1[4]; s16x8 xb0[4], xb1[4];
  f32x4 ya0[4], ya1[4]; s16x8 yb0[4], yb1[4];
  f32x4 acc0 = {0, 0, 0, 0}, acc1 = {0, 0, 0, 0};

  const float* apx = ap;                     // -> group 0, advances by 2 groups
  const float* apy = ap + 128;               // -> group 1
  const unsigned short* b0x = bp0;
  const unsigned short* b0y = bp0 + 4 * 512;
  const unsigned short* b1x = bp1;
  const unsigned short* b1y = bp1 + 4 * 512;

#define LDG(a0v, a1v, b0v, b1v, apv, b0pv, b1pv)                 \
  {                                                              \
    _Pragma("unroll") for (int c = 0; c < 4; ++c) {              \
      a0v[c] = *(const f32x4*)(apv + c * 32);                    \
      a1v[c] = *(const f32x4*)(apv + c * 32 + 4);                \
      b0v[c] = *(const s16x8*)(b0pv + c * 512);                  \
      b1v[c] = *(const s16x8*)(b1pv + c * 512);                  \
    }                                                            \
    apv += 256; b0pv += 4096; b1pv += 4096;                      \
  }

#define CMP(a0v, a1v, b0v, b1v)                                              \
  {                                                                          \
    _Pragma("unroll") for (int c = 0; c < 4; ++c) {                          \
      s16x8 af = pack8f(a0v[c], a1v[c]);                                     \
      acc0 = __builtin_amdgcn_mfma_f32_16x16x32_bf16(af, b0v[c], acc0, 0, 0, 0); \
      acc1 = __builtin_amdgcn_mfma_f32_16x16x32_bf16(af, b1v[c], acc1, 0, 0, 0); \
    }                                                                        \
  }

  LDG(xa0, xa1, xb0, xb1, apx, b0x, b1x);    // group 0
  LDG(ya0, ya1, yb0, yb1, apy, b0y, b1y);    // group 1

#pragma unroll 1
  for (int g = 0; g < 32; g += 2) {
    CMP(xa0, xa1, xb0, xb1);
    if (g + 2 < 32) LDG(xa0, xa1, xb0, xb1, apx, b0x, b1x);
    CMP(ya0, ya1, yb0, yb1);
    if (g + 3 < 32) LDG(ya0, ya1, yb0, yb1, apy, b0y, b1y);
  }
#undef LDG
#undef CMP

  if constexpr (EPI == 0) {
    // fragment(n,k): n = t*16 + l16, k = mblk*32 + msub*16 + quad*4 + r
    //   kc = mblk ; (k>>3)&3 = msub*2 + (quad>>1) ; k&7 = (quad&1)*4 + r
    const int qp = msub * 2 + (quad >> 1);
    const int j0 = (quad & 1) * 4;
    long i0 = ((long)(t0 * 128 + mblk)) * 512 + (qp * 16 + l16) * 8 + j0;
    long i1 = ((long)((t0 + 1) * 128 + mblk)) * 512 + (qp * 16 + l16) * 8 + j0;
    *(ushort4*)(CF + i0) = cvt4(acc0);
    *(ushort4*)(CF + i1) = cvt4(acc1);
  } else {
    const float aLv = aLp[0], aHv = aHp[0];
    const int mr = mblk * 32 + msub * 16 + quad * 4;
    const int c0 = t0 * 16 + l16;
    const int c1 = c0 + 16;
#pragma unroll
    for (int r = 0; r < 4; ++r) {
      int row = mr + r;
      outF[(long)row * DD + c0] =
          aHv * acc0[r] + aLv * (Hl[(long)row * DD + c0] + bconv[c0]);
      outF[(long)row * DD + c1] =
          aHv * acc1[r] + aLv * (Hl[(long)row * DD + c1] + bconv[c1]);
    }
  }
}

// ---------------------------------------------------------------------------
// launcher
// ---------------------------------------------------------------------------
extern "C" void kernel_launch(void* const* d_in, const int* in_sizes, int n_in,
                              void* d_out, int out_size, void* d_ws, size_t ws_size,
                              hipStream_t stream) {
  const float* x     = (const float*)d_in[0];
  const int*   ei    = (const int*)d_in[1];
  const float* lap   = (const float*)d_in[2];
  const float* dinv  = (const float*)d_in[3];
  const float* Wh    = (const float*)d_in[4];
  const float* Wc    = (const float*)d_in[5];
  const float* bconv = (const float*)d_in[6];
  const float* aL    = (const float*)d_in[7];
  const float* aH    = (const float*)d_in[8];
  float* out = (float*)d_out;
  char* ws = (char*)d_ws;

  int* deg        = (int*)(ws);                          // 16 KB
  int* cursor     = (int*)(ws + (16 << 10));             // 16 KB
  int* row_start  = (int*)(ws + (32 << 10));             // 16.4 KB
  int* csr        = (int*)(ws + (64 << 10));             // 512 KB
  float* dis      = (float*)(ws + (576 << 10));          // 16 KB
  unsigned short* WFh = (unsigned short*)(ws + (1l << 20));               // 128 KB
  unsigned short* WFc = (unsigned short*)(ws + (1l << 20) + (128 << 10)); // 128 KB
  unsigned short* RF  = (unsigned short*)(ws + (2l << 20));  // 2 MB fragment layout
  unsigned short* T1F = (unsigned short*)(ws + (4l << 20));  // 2 MB
  unsigned short* T2F = (unsigned short*)(ws + (6l << 20));  // 2 MB
  float* XWs = (float*)(ws + (8l << 20));                    // 4 MB
  float* Hl  = (float*)(ws + (12l << 20));                   // 4 MB

  hipMemsetAsync(ws, 0, 32 << 10, stream);   // deg + cursor

  k_prep<<<1024, 256, 0, stream>>>(ei, deg, Wh, Wc, WFh, WFc);
  k_scan<<<1, 1024, 0, stream>>>(deg, row_start, dis);
  k_scatter<<<512, 256, 0, stream>>>(ei, row_start, cursor, csr);
  k_xw<<<256, 512, 0, stream>>>(x, WFh, WFc, RF, XWs, dis);
  k_agg<<<4096, 256, 0, stream>>>(XWs, row_start, csr, dis, Hl);

  k_mm2<0><<<256, 512, 0, stream>>>(dinv, RF, T1F, nullptr, nullptr, nullptr, nullptr, nullptr);
  k_mm2<0><<<256, 512, 0, stream>>>(lap, T1F, T2F, nullptr, nullptr, nullptr, nullptr, nullptr);
  k_mm2<3><<<256, 512, 0, stream>>>(dinv, T2F, nullptr, out, Hl, bconv, aL, aH);
}

// Round 3
// 310.127 us; speedup vs baseline: 1.3131x; 1.3131x over previous
//
#include <hip/hip_runtime.h>

#define NN 4096
#define DD 256
#define EE 131072

typedef __attribute__((ext_vector_type(8))) short s16x8;
typedef __attribute__((ext_vector_type(4))) float f32x4;

__device__ __forceinline__ unsigned short f2bf(float f) {
  unsigned u = __builtin_bit_cast(unsigned, f);
  u += 0x7FFFu + ((u >> 16) & 1u);
  return (unsigned short)(u >> 16);
}

__device__ __forceinline__ ushort4 cvt4(f32x4 v) {
  ushort4 r;
  r.x = f2bf(v[0]); r.y = f2bf(v[1]); r.z = f2bf(v[2]); r.w = f2bf(v[3]);
  return r;
}

// round-half-up fp32->bf16 pair pack: 2 adds + 1 v_perm
__device__ __forceinline__ unsigned cvt2_rhu(float a, float b) {
  unsigned ua = __builtin_bit_cast(unsigned, a) + 0x8000u;
  unsigned ub = __builtin_bit_cast(unsigned, b) + 0x8000u;
  return __builtin_amdgcn_perm(ub, ua, 0x07060302u);
}

__device__ __forceinline__ uint4 pack8(f32x4 a, f32x4 b) {
  uint4 r;
  r.x = cvt2_rhu(a[0], a[1]); r.y = cvt2_rhu(a[2], a[3]);
  r.z = cvt2_rhu(b[0], b[1]); r.w = cvt2_rhu(b[2], b[3]);
  return r;
}

__device__ __forceinline__ s16x8 pack8f(f32x4 a, f32x4 b) {
  uint4 p = pack8(a, b);
  return __builtin_bit_cast(s16x8, p);
}

// async global->LDS, 16B per lane; LDS dest must be wave-uniform base + lane*16
__device__ __forceinline__ void gl2lds(const float* g, float* l) {
  __builtin_amdgcn_global_load_lds(
      (const __attribute__((address_space(1))) unsigned*)g,
      (__attribute__((address_space(3))) unsigned*)l, 16, 0, 0);
}

// B fragment layout (consumed by mfma_16x16x32_bf16 B-operand):
//   element (n, k) of a 256-col operand lives at ushort index
//   (tile*128 + kc)*512 + (quad*16 + (n&15))*8 + (k&7)
//   tile = n>>4, kc = k>>5, quad = (k>>3)&3.  One wave chunk-load = 1KB coalesced.

// ---------------------------------------------------------------------------
// K1: count in-degrees + write both W matrices in B-fragment layout (bf16)
// ---------------------------------------------------------------------------
__global__ void k_prep(const int* __restrict__ ei, int* __restrict__ deg,
                       const float* __restrict__ Wh, const float* __restrict__ Wc,
                       unsigned short* __restrict__ WFh, unsigned short* __restrict__ WFc) {
  int t = blockIdx.x * 256 + threadIdx.x;
  if (t < EE) {
    atomicAdd(&deg[ei[EE + t]], 1);
  } else {
    int idx = t - EE;                 // 0..131071
    int which = idx >> 16;            // 0: W_high, 1: W_conv
    int r = idx & 65535;
    int n = r & 255, k = r >> 8;      // consecutive threads -> consecutive n (coalesced read)
    const float* W = which ? Wc : Wh;
    unsigned short* WF = which ? WFc : WFh;
    long fidx = ((long)((n >> 4) * 8 + (k >> 5))) * 512 +
                (((k >> 3) & 3) * 16 + (n & 15)) * 8 + (k & 7);
    WF[fidx] = f2bf(W[k * 256 + n]);  // fragment(n,k) = W[k][n]
  }
}

// ---------------------------------------------------------------------------
// K2: exclusive scan of deg -> row_start[4097]; dis = rsqrt(deg+1)
// ---------------------------------------------------------------------------
__global__ void k_scan(const int* __restrict__ deg, int* __restrict__ row_start,
                       float* __restrict__ dis) {
  __shared__ int part[1024];
  int t = threadIdx.x;
  int d0 = deg[4 * t + 0], d1 = deg[4 * t + 1], d2 = deg[4 * t + 2], d3 = deg[4 * t + 3];
  int s = d0 + d1 + d2 + d3;
  part[t] = s;
  __syncthreads();
  for (int off = 1; off < 1024; off <<= 1) {
    int add = (t >= off) ? part[t - off] : 0;
    __syncthreads();
    part[t] += add;
    __syncthreads();
  }
  int base = part[t] - s;
  row_start[4 * t + 0] = base;
  row_start[4 * t + 1] = base + d0;
  row_start[4 * t + 2] = base + d0 + d1;
  row_start[4 * t + 3] = base + d0 + d1 + d2;
  if (t == 1023) row_start[4096] = part[t];
  dis[4 * t + 0] = rsqrtf((float)d0 + 1.0f);
  dis[4 * t + 1] = rsqrtf((float)d1 + 1.0f);
  dis[4 * t + 2] = rsqrtf((float)d2 + 1.0f);
  dis[4 * t + 3] = rsqrtf((float)d3 + 1.0f);
}

// ---------------------------------------------------------------------------
// K3: scatter edges into CSR buckets
// ---------------------------------------------------------------------------
__global__ void k_scatter(const int* __restrict__ ei, const int* __restrict__ row_start,
                          int* __restrict__ cursor, int* __restrict__ csr) {
  int e = blockIdx.x * 256 + threadIdx.x;
  if (e < EE) {
    int s = ei[e];
    int d = ei[EE + e];
    int p = atomicAdd(&cursor[d], 1);
    csr[row_start[d] + p] = s;
  }
}

// ---------------------------------------------------------------------------
// K4: RF = frag(relu(x @ W_high))  and  XWs[m][n] = dis[m] * (x @ W_conv)[m][n]
//     grid 256 (16-row M-tiles), block 512. waves 0-3: high, 4-7: conv.
// ---------------------------------------------------------------------------
__global__ __launch_bounds__(512) void k_xw(const float* __restrict__ x,
                                            const unsigned short* __restrict__ WFh,
                                            const unsigned short* __restrict__ WFc,
                                            unsigned short* __restrict__ RF,
                                            float* __restrict__ XWs,
                                            const float* __restrict__ dis) {
  __shared__ alignas(16) unsigned short Abuf[16][264];
  const int tid = threadIdx.x;
  const int w = tid >> 6, lane = tid & 63;
  const int quad = lane >> 4, l16 = lane & 15, quad8 = quad * 8;
  const int m0 = blockIdx.x * 16;

  {
    int srow = tid >> 5, scolf = (tid & 31) * 8;
    const float* ap = x + (long)(m0 + srow) * DD + scolf;
    f32x4 a0 = *(const f32x4*)ap;
    f32x4 a1 = *(const f32x4*)(ap + 4);
    *(uint4*)&Abuf[srow][scolf] = pack8(a0, a1);
  }
  __syncthreads();

  const bool hi = (w < 4);
  const int wo = hi ? w : (w - 4);
  const unsigned short* WF = hi ? WFh : WFc;
  const unsigned short* bp = WF + lane * 8;

  f32x4 acc[4] = {{0,0,0,0},{0,0,0,0},{0,0,0,0},{0,0,0,0}};
#pragma unroll
  for (int q = 0; q < 8; ++q) {
    s16x8 af = *(const s16x8*)&Abuf[l16][q * 32 + quad8];
#pragma unroll
    for (int s = 0; s < 4; ++s) {
      s16x8 bf = *(const s16x8*)(bp + ((long)((4 * wo + s) * 8 + q)) * 512);
      acc[s] = __builtin_amdgcn_mfma_f32_16x16x32_bf16(af, bf, acc[s], 0, 0, 0);
    }
  }

  if (hi) {
    const int kc = m0 >> 5;
    const int qp = ((m0 >> 4) & 1) * 2 + (quad >> 1);
    const int j0 = (quad & 1) * 4;
#pragma unroll
    for (int s = 0; s < 4; ++s) {
      int t = 4 * wo + s;
      f32x4 v = acc[s];
      f32x4 z;
      z[0] = v[0] > 0.f ? v[0] : 0.f;
      z[1] = v[1] > 0.f ? v[1] : 0.f;
      z[2] = v[2] > 0.f ? v[2] : 0.f;
      z[3] = v[3] > 0.f ? v[3] : 0.f;
      long idx = ((long)(t * 128 + kc)) * 512 + (qp * 16 + l16) * 8 + j0;
      *(ushort4*)(RF + idx) = cvt4(z);
    }
  } else {
    float dm[4];
#pragma unroll
    for (int r = 0; r < 4; ++r) dm[r] = dis[m0 + quad * 4 + r];
#pragma unroll
    for (int s = 0; s < 4; ++s) {
      int col = 64 * wo + 16 * s + l16;
#pragma unroll
      for (int r = 0; r < 4; ++r)
        XWs[(long)(m0 + quad * 4 + r) * DD + col] = dm[r] * acc[s][r];
    }
  }
}

// ---------------------------------------------------------------------------
// K5: GCN aggregation, dis pre-multiplied into XWs; unroll-by-4 gathers
// ---------------------------------------------------------------------------
__global__ void k_agg(const float* __restrict__ XWs, const int* __restrict__ row_start,
                      const int* __restrict__ csr, const float* __restrict__ dis,
                      float* __restrict__ Hl) {
  const int i = blockIdx.x;
  const int t = threadIdx.x;
  const int b0 = row_start[i], b1 = row_start[i + 1];
  float acc = XWs[(long)i * DD + t];   // self loop
  int j = b0;
  for (; j + 4 <= b1; j += 4) {
    int s0 = csr[j], s1 = csr[j + 1], s2 = csr[j + 2], s3 = csr[j + 3];
    float v0 = XWs[(long)s0 * DD + t];
    float v1 = XWs[(long)s1 * DD + t];
    float v2 = XWs[(long)s2 * DD + t];
    float v3 = XWs[(long)s3 * DD + t];
    acc += (v0 + v1) + (v2 + v3);
  }
  for (; j < b1; ++j) acc += XWs[(long)csr[j] * DD + t];
  Hl[(long)i * DD + t] = dis[i] * acc;
}

// ---------------------------------------------------------------------------
// K6: C[4096 x 256] = A[4096 x 4096](fp32) @ B, B in fragment layout (bf16).
//     T3+T4 structure (counted vmcnt, raw s_barrier, global_load_lds):
//     - 32 K-stages of BK=128; A fp32 staged into a 3-buffer LDS ring via
//       global_load_lds (2 x 16B/thread/stage), source addresses pre-swizzled
//       (granule col4 ^= row&7) so ds_read_b128 fragments are bank-uniform.
//     - per-stage: asm vmcnt(2) [retires A(s)+B(s), keeps A(s+1) in flight
//       2 full stages] -> raw s_barrier -> ds_read A(s) -> issue B(s+1)
//       (global->reg, L2-resident) -> issue A_lds(s+2) -> pack fp32->bf16 ->
//       8 MFMA.  vmcnt never drains to 0 in the loop: loads cross barriers.
//     grid 256 = 128 m-blocks (32 rows) x 2 n-halves; 8 waves:
//     wave -> (msub = w&1: 16-row half, nsub = w>>1: n-tiles t0, t0+1).
//     EPI 0: write C in fragment layout (next mm's B).  EPI 3: fused final.
// ---------------------------------------------------------------------------
template <int EPI>
__global__ __launch_bounds__(512) void k_mm2(const float* __restrict__ A,
                                             const unsigned short* __restrict__ BF,
                                             unsigned short* __restrict__ CF,
                                             float* __restrict__ outF,
                                             const float* __restrict__ Hl,
                                             const float* __restrict__ bconv,
                                             const float* __restrict__ aLp,
                                             const float* __restrict__ aHp) {
  __shared__ alignas(16) float As[3][32 * 128];   // 3 x 16KB ring
  const int tid = threadIdx.x;
  const int w = tid >> 6, lane = tid & 63;
  const int quad = lane >> 4, l16 = lane & 15;
  const int mblk = blockIdx.x & 127, nhalf = blockIdx.x >> 7;
  const int msub = w & 1, nsub = w >> 1;
  const int m0 = mblk * 32;
  const int t0 = nhalf * 8 + nsub * 2;

  // --- staging addresses: thread t owns LDS granules t and t+512 of each tile.
  // granule position p holds A[row = p>>5][col4 = (p&31) ^ (row&7)] (4 floats).
  // rows r0 and r0+16 share (row&7), so both use the same source column.
  const int r0 = tid >> 5;
  const int cg = (tid & 31) ^ (r0 & 7);
  const float* srcA0 = A + (long)(m0 + r0) * NN + cg * 4;
  const float* srcA1 = A + (long)(m0 + r0 + 16) * NN + cg * 4;

  // --- compute-side ds_read offsets (floats): fragment chunk c, half e:
  //   off = row*128 + c*32 + ((2*quad+e) ^ (row&7))*4
  const int row = msub * 16 + l16;
  const int r7 = row & 7;
  const int arow_off = row * 128;
  const int g0 = ((2 * quad) ^ r7) * 4;
  const int g1 = ((2 * quad + 1) ^ r7) * 4;

  const unsigned short* bq0 = BF + ((long)t0 * 128) * 512 + lane * 8;
  const unsigned short* bq1 = bq0 + 128l * 512;

  f32x4 acc0 = {0, 0, 0, 0}, acc1 = {0, 0, 0, 0};
  s16x8 bA0[4], bA1[4], bB0[4], bB1[4];

  // prologue: stage A(0)->buf0, A(1)->buf1, B(0)->set A
  gl2lds(srcA0, &As[0][0] + tid * 4);
  gl2lds(srcA1, &As[0][0] + 2048 + tid * 4);
  gl2lds(srcA0 + 128, &As[1][0] + tid * 4);
  gl2lds(srcA1 + 128, &As[1][0] + 2048 + tid * 4);
#pragma unroll
  for (int c = 0; c < 4; ++c) {
    bA0[c] = *(const s16x8*)(bq0 + c * 512);
    bA1[c] = *(const s16x8*)(bq1 + c * 512);
  }

// one pipeline stage.  s: runtime stage index, CUR: read-buffer index (0..2),
// BU*: B regs consumed this stage, BL*: B regs loaded for next stage.
#define STAGE(s, CUR, BU0, BU1, BL0, BL1)                                      \
  {                                                                            \
    asm volatile("s_waitcnt vmcnt(2)" ::: "memory");                           \
    __builtin_amdgcn_s_barrier();                                              \
    const float* ar = &As[CUR][0] + arow_off;                                  \
    f32x4 alo[4], ahi[4];                                                      \
    _Pragma("unroll") for (int c = 0; c < 4; ++c) {                            \
      alo[c] = *(const f32x4*)(ar + c * 32 + g0);                              \
      ahi[c] = *(const f32x4*)(ar + c * 32 + g1);                              \
    }                                                                          \
    {                                                                          \
      long kb = (long)(((s) + 1 < 32) ? (s) + 1 : 31) * 2048;                  \
      _Pragma("unroll") for (int c = 0; c < 4; ++c) {                          \
        BL0[c] = *(const s16x8*)(bq0 + kb + c * 512);                          \
        BL1[c] = *(const s16x8*)(bq1 + kb + c * 512);                          \
      }                                                                        \
    }                                                                          \
    {                                                                          \
      long sa = ((s) + 2 < 32) ? (s) + 2 : 31;                                 \
      int wb = (CUR) + 2 >= 3 ? (CUR)-1 : (CUR) + 2;                           \
      gl2lds(srcA0 + sa * 128, &As[wb][0] + tid * 4);                          \
      gl2lds(srcA1 + sa * 128, &As[wb][0] + 2048 + tid * 4);                   \
    }                                                                          \
    _Pragma("unroll") for (int c = 0; c < 4; ++c) {                            \
      s16x8 af = pack8f(alo[c], ahi[c]);                                       \
      acc0 = __builtin_amdgcn_mfma_f32_16x16x32_bf16(af, BU0[c], acc0, 0, 0, 0); \
      acc1 = __builtin_amdgcn_mfma_f32_16x16x32_bf16(af, BU1[c], acc1, 0, 0, 0); \
    }                                                                          \
  }

  int cur = 0;
#pragma unroll 1
  for (int s2 = 0; s2 < 16; ++s2) {
    const int s = 2 * s2;
    STAGE(s, cur, bA0, bA1, bB0, bB1);
    const int cn = (cur + 1 == 3) ? 0 : cur + 1;
    STAGE(s + 1, cn, bB0, bB1, bA0, bA1);
    cur = (cn + 1 == 3) ? 0 : cn + 1;
  }
#undef STAGE

  if constexpr (EPI == 0) {
    // fragment(n,k): n = t*16 + l16, k = mblk*32 + msub*16 + quad*4 + r
    //   kc = mblk ; (k>>3)&3 = msub*2 + (quad>>1) ; k&7 = (quad&1)*4 + r
    const int qp = msub * 2 + (quad >> 1);
    const int j0 = (quad & 1) * 4;
    long i0 = ((long)(t0 * 128 + mblk)) * 512 + (qp * 16 + l16) * 8 + j0;
    long i1 = ((long)((t0 + 1) * 128 + mblk)) * 512 + (qp * 16 + l16) * 8 + j0;
    *(ushort4*)(CF + i0) = cvt4(acc0);
    *(ushort4*)(CF + i1) = cvt4(acc1);
  } else {
    const float aLv = aLp[0], aHv = aHp[0];
    const int mr = m0 + msub * 16 + quad * 4;
    const int c0 = t0 * 16 + l16;
    const int c1 = c0 + 16;
#pragma unroll
    for (int r = 0; r < 4; ++r) {
      int rr = mr + r;
      outF[(long)rr * DD + c0] =
          aHv * acc0[r] + aLv * (Hl[(long)rr * DD + c0] + bconv[c0]);
      outF[(long)rr * DD + c1] =
          aHv * acc1[r] + aLv * (Hl[(long)rr * DD + c1] + bconv[c1]);
    }
  }
}

// ---------------------------------------------------------------------------
// launcher
// ---------------------------------------------------------------------------
extern "C" void kernel_launch(void* const* d_in, const int* in_sizes, int n_in,
                              void* d_out, int out_size, void* d_ws, size_t ws_size,
                              hipStream_t stream) {
  const float* x     = (const float*)d_in[0];
  const int*   ei    = (const int*)d_in[1];
  const float* lap   = (const float*)d_in[2];
  const float* dinv  = (const float*)d_in[3];
  const float* Wh    = (const float*)d_in[4];
  const float* Wc    = (const float*)d_in[5];
  const float* bconv = (const float*)d_in[6];
  const float* aL    = (const float*)d_in[7];
  const float* aH    = (const float*)d_in[8];
  float* out = (float*)d_out;
  char* ws = (char*)d_ws;

  int* deg        = (int*)(ws);                          // 16 KB
  int* cursor     = (int*)(ws + (16 << 10));             // 16 KB
  int* row_start  = (int*)(ws + (32 << 10));             // 16.4 KB
  int* csr        = (int*)(ws + (64 << 10));             // 512 KB
  float* dis      = (float*)(ws + (576 << 10));          // 16 KB
  unsigned short* WFh = (unsigned short*)(ws + (1l << 20));               // 128 KB
  unsigned short* WFc = (unsigned short*)(ws + (1l << 20) + (128 << 10)); // 128 KB
  unsigned short* RF  = (unsigned short*)(ws + (2l << 20));  // 2 MB fragment layout
  unsigned short* T1F = (unsigned short*)(ws + (4l << 20));  // 2 MB
  unsigned short* T2F = (unsigned short*)(ws + (6l << 20));  // 2 MB
  float* XWs = (float*)(ws + (8l << 20));                    // 4 MB
  float* Hl  = (float*)(ws + (12l << 20));                   // 4 MB

  hipMemsetAsync(ws, 0, 32 << 10, stream);   // deg + cursor

  k_prep<<<1024, 256, 0, stream>>>(ei, deg, Wh, Wc, WFh, WFc);
  k_scan<<<1, 1024, 0, stream>>>(deg, row_start, dis);
  k_scatter<<<512, 256, 0, stream>>>(ei, row_start, cursor, csr);
  k_xw<<<256, 512, 0, stream>>>(x, WFh, WFc, RF, XWs, dis);
  k_agg<<<4096, 256, 0, stream>>>(XWs, row_start, csr, dis, Hl);

  k_mm2<0><<<256, 512, 0, stream>>>(dinv, RF, T1F, nullptr, nullptr, nullptr, nullptr, nullptr);
  k_mm2<0><<<256, 512, 0, stream>>>(lap, T1F, T2F, nullptr, nullptr, nullptr, nullptr, nullptr);
  k_mm2<3><<<256, 512, 0, stream>>>(dinv, T2F, nullptr, out, Hl, bconv, aL, aH);
}

// Round 4
// 282.087 us; speedup vs baseline: 1.4437x; 1.0994x over previous
//
#include <hip/hip_runtime.h>

#define NN 4096
#define DD 256
#define EE 131072

typedef __attribute__((ext_vector_type(8))) short s16x8;
typedef __attribute__((ext_vector_type(4))) float f32x4;

__device__ __forceinline__ unsigned short f2bf(float f) {
  unsigned u = __builtin_bit_cast(unsigned, f);
  u += 0x7FFFu + ((u >> 16) & 1u);
  return (unsigned short)(u >> 16);
}

__device__ __forceinline__ ushort4 cvt4(f32x4 v) {
  ushort4 r;
  r.x = f2bf(v[0]); r.y = f2bf(v[1]); r.z = f2bf(v[2]); r.w = f2bf(v[3]);
  return r;
}

// round-half-up fp32->bf16 pair pack: 2 adds + 1 v_perm
__device__ __forceinline__ unsigned cvt2_rhu(float a, float b) {
  unsigned ua = __builtin_bit_cast(unsigned, a) + 0x8000u;
  unsigned ub = __builtin_bit_cast(unsigned, b) + 0x8000u;
  return __builtin_amdgcn_perm(ub, ua, 0x07060302u);
}

__device__ __forceinline__ uint4 pack8(f32x4 a, f32x4 b) {
  uint4 r;
  r.x = cvt2_rhu(a[0], a[1]); r.y = cvt2_rhu(a[2], a[3]);
  r.z = cvt2_rhu(b[0], b[1]); r.w = cvt2_rhu(b[2], b[3]);
  return r;
}

// B fragment layout (consumed by mfma_16x16x32_bf16 B-operand):
//   element (n, k) of a 256-col operand lives at ushort index
//   (tile*128 + kc)*512 + (quad*16 + (n&15))*8 + (k&7)
//   tile = n>>4, kc = k>>5, quad = (k>>3)&3.  One wave chunk-load = 1KB coalesced.

// ---------------------------------------------------------------------------
// K1: count in-degrees + write both W matrices in B-fragment layout (bf16)
// ---------------------------------------------------------------------------
__global__ void k_prep(const int* __restrict__ ei, int* __restrict__ deg,
                       const float* __restrict__ Wh, const float* __restrict__ Wc,
                       unsigned short* __restrict__ WFh, unsigned short* __restrict__ WFc) {
  int t = blockIdx.x * 256 + threadIdx.x;
  if (t < EE) {
    atomicAdd(&deg[ei[EE + t]], 1);
  } else {
    int idx = t - EE;                 // 0..131071
    int which = idx >> 16;            // 0: W_high, 1: W_conv
    int r = idx & 65535;
    int n = r & 255, k = r >> 8;      // consecutive threads -> consecutive n (coalesced read)
    const float* W = which ? Wc : Wh;
    unsigned short* WF = which ? WFc : WFh;
    long fidx = ((long)((n >> 4) * 8 + (k >> 5))) * 512 +
                (((k >> 3) & 3) * 16 + (n & 15)) * 8 + (k & 7);
    WF[fidx] = f2bf(W[k * 256 + n]);  // fragment(n,k) = W[k][n]
  }
}

// ---------------------------------------------------------------------------
// K2: exclusive scan of deg -> row_start[4097]; dis = rsqrt(deg+1)
// ---------------------------------------------------------------------------
__global__ void k_scan(const int* __restrict__ deg, int* __restrict__ row_start,
                       float* __restrict__ dis) {
  __shared__ int part[1024];
  int t = threadIdx.x;
  int d0 = deg[4 * t + 0], d1 = deg[4 * t + 1], d2 = deg[4 * t + 2], d3 = deg[4 * t + 3];
  int s = d0 + d1 + d2 + d3;
  part[t] = s;
  __syncthreads();
  for (int off = 1; off < 1024; off <<= 1) {
    int add = (t >= off) ? part[t - off] : 0;
    __syncthreads();
    part[t] += add;
    __syncthreads();
  }
  int base = part[t] - s;
  row_start[4 * t + 0] = base;
  row_start[4 * t + 1] = base + d0;
  row_start[4 * t + 2] = base + d0 + d1;
  row_start[4 * t + 3] = base + d0 + d1 + d2;
  if (t == 1023) row_start[4096] = part[t];
  dis[4 * t + 0] = rsqrtf((float)d0 + 1.0f);
  dis[4 * t + 1] = rsqrtf((float)d1 + 1.0f);
  dis[4 * t + 2] = rsqrtf((float)d2 + 1.0f);
  dis[4 * t + 3] = rsqrtf((float)d3 + 1.0f);
}

// ---------------------------------------------------------------------------
// K3: scatter edges into CSR buckets
// ---------------------------------------------------------------------------
__global__ void k_scatter(const int* __restrict__ ei, const int* __restrict__ row_start,
                          int* __restrict__ cursor, int* __restrict__ csr) {
  int e = blockIdx.x * 256 + threadIdx.x;
  if (e < EE) {
    int s = ei[e];
    int d = ei[EE + e];
    int p = atomicAdd(&cursor[d], 1);
    csr[row_start[d] + p] = s;
  }
}

// ---------------------------------------------------------------------------
// K4: RF = frag(relu(x @ W_high))  and  XWs[m][n] = dis[m] * (x @ W_conv)[m][n]
//     grid 256 (16-row M-tiles), block 512. waves 0-3: high, 4-7: conv.
// ---------------------------------------------------------------------------
__global__ __launch_bounds__(512) void k_xw(const float* __restrict__ x,
                                            const unsigned short* __restrict__ WFh,
                                            const unsigned short* __restrict__ WFc,
                                            unsigned short* __restrict__ RF,
                                            float* __restrict__ XWs,
                                            const float* __restrict__ dis) {
  __shared__ alignas(16) unsigned short Abuf[16][264];
  const int tid = threadIdx.x;
  const int w = tid >> 6, lane = tid & 63;
  const int quad = lane >> 4, l16 = lane & 15, quad8 = quad * 8;
  const int m0 = blockIdx.x * 16;

  {
    int srow = tid >> 5, scolf = (tid & 31) * 8;
    const float* ap = x + (long)(m0 + srow) * DD + scolf;
    f32x4 a0 = *(const f32x4*)ap;
    f32x4 a1 = *(const f32x4*)(ap + 4);
    *(uint4*)&Abuf[srow][scolf] = pack8(a0, a1);
  }
  __syncthreads();

  const bool hi = (w < 4);
  const int wo = hi ? w : (w - 4);
  const unsigned short* WF = hi ? WFh : WFc;
  const unsigned short* bp = WF + lane * 8;

  f32x4 acc[4] = {{0,0,0,0},{0,0,0,0},{0,0,0,0},{0,0,0,0}};
#pragma unroll
  for (int q = 0; q < 8; ++q) {
    s16x8 af = *(const s16x8*)&Abuf[l16][q * 32 + quad8];
#pragma unroll
    for (int s = 0; s < 4; ++s) {
      s16x8 bf = *(const s16x8*)(bp + ((long)((4 * wo + s) * 8 + q)) * 512);
      acc[s] = __builtin_amdgcn_mfma_f32_16x16x32_bf16(af, bf, acc[s], 0, 0, 0);
    }
  }

  if (hi) {
    const int kc = m0 >> 5;
    const int qp = ((m0 >> 4) & 1) * 2 + (quad >> 1);
    const int j0 = (quad & 1) * 4;
#pragma unroll
    for (int s = 0; s < 4; ++s) {
      int t = 4 * wo + s;
      f32x4 v = acc[s];
      f32x4 z;
      z[0] = v[0] > 0.f ? v[0] : 0.f;
      z[1] = v[1] > 0.f ? v[1] : 0.f;
      z[2] = v[2] > 0.f ? v[2] : 0.f;
      z[3] = v[3] > 0.f ? v[3] : 0.f;
      long idx = ((long)(t * 128 + kc)) * 512 + (qp * 16 + l16) * 8 + j0;
      *(ushort4*)(RF + idx) = cvt4(z);
    }
  } else {
    float dm[4];
#pragma unroll
    for (int r = 0; r < 4; ++r) dm[r] = dis[m0 + quad * 4 + r];
#pragma unroll
    for (int s = 0; s < 4; ++s) {
      int col = 64 * wo + 16 * s + l16;
#pragma unroll
      for (int r = 0; r < 4; ++r)
        XWs[(long)(m0 + quad * 4 + r) * DD + col] = dm[r] * acc[s][r];
    }
  }
}

// ---------------------------------------------------------------------------
// K5: GCN aggregation, dis pre-multiplied into XWs; unroll-by-4 gathers
// ---------------------------------------------------------------------------
__global__ void k_agg(const float* __restrict__ XWs, const int* __restrict__ row_start,
                      const int* __restrict__ csr, const float* __restrict__ dis,
                      float* __restrict__ Hl) {
  const int i = blockIdx.x;
  const int t = threadIdx.x;
  const int b0 = row_start[i], b1 = row_start[i + 1];
  float acc = XWs[(long)i * DD + t];   // self loop
  int j = b0;
  for (; j + 4 <= b1; j += 4) {
    int s0 = csr[j], s1 = csr[j + 1], s2 = csr[j + 2], s3 = csr[j + 3];
    float v0 = XWs[(long)s0 * DD + t];
    float v1 = XWs[(long)s1 * DD + t];
    float v2 = XWs[(long)s2 * DD + t];
    float v3 = XWs[(long)s3 * DD + t];
    acc += (v0 + v1) + (v2 + v3);
  }
  for (; j < b1; ++j) acc += XWs[(long)csr[j] * DD + t];
  Hl[(long)i * DD + t] = dis[i] * acc;
}

// ---------------------------------------------------------------------------
// K6: C[4096 x 256] = A[4096 x 4096](fp32) @ B, B in fragment layout (bf16).
//     FEWER, FATTER STAGES: BK=512 -> 8 stages (R0 16 @2.8us, R3 32 @1.8us:
//     time ~ stages x (fixed latency + traffic); cut stage count).
//     A staged global->reg (8 x f32x4/thread) with sched_barrier(0) fence so
//     hipcc cannot sink the loads next to their use (R0 collapsed to VGPR=36,
//     fully serializing each stage).  Pack fp32->bf16 in-reg, ds_write to
//     XOR-swizzled LDS (granule16 ^= row&7 -> all 8 bank positions hit,
//     minimum-phase conflict-free for both write and frag read).
//     LDS 2 x 32 x 512 bf16 = 64 KB double buffer, one __syncthreads/stage.
//     grid 256 = 128 m-blocks (32 rows) x 2 n-halves (XCD-paired);
//     8 waves: msub = w&1 (16-row half), nsub = w>>1 (n-tiles t0, t0+1).
//     EPI 0: write C in fragment layout (next mm's B).  EPI 3: fused final.
// ---------------------------------------------------------------------------
template <int EPI>
__global__ __launch_bounds__(512) void k_mm2(const float* __restrict__ A,
                                             const unsigned short* __restrict__ BF,
                                             unsigned short* __restrict__ CF,
                                             float* __restrict__ outF,
                                             const float* __restrict__ Hl,
                                             const float* __restrict__ bconv,
                                             const float* __restrict__ aLp,
                                             const float* __restrict__ aHp) {
  __shared__ alignas(16) unsigned short As[2][32 * 512];   // 64 KB double buffer
  const int tid = threadIdx.x;
  const int w = tid >> 6, lane = tid & 63;
  const int quad = lane >> 4, l16 = lane & 15;
  const int mblk = blockIdx.x & 127, nhalf = blockIdx.x >> 7;
  const int msub = w & 1, nsub = w >> 1;
  const int m0 = mblk * 32;
  const int t0 = nhalf * 8 + nsub * 2;

  // --- staging: thread t owns row (t>>4), granules {t&15 + 16j}, j=0..3.
  //     granule = 16B = 8 bf16 = 8 source floats; stored at (g ^ (row&7)).
  //     16 threads/row -> granules of one j cover all 16 positions; XOR by
  //     row&7 keeps every 8-position bank window uniformly hit.
  const int srow = tid >> 4;          // 0..31
  const int sg = tid & 15;
  const int sswz = srow & 7;
  const float* asrc = A + (long)(m0 + srow) * NN + sg * 8;
  unsigned short* const wbase0 = &As[0][srow * 512];
  unsigned short* const wbase1 = &As[1][srow * 512];

  // --- compute-side: wave reads row = msub*16 + l16; chunk c (32 k), quad q
  //     -> granule (c*4 + q) ^ (row&7).
  const int row = msub * 16 + l16;
  const int r7 = row & 7;
  const unsigned short* const rbase0 = &As[0][row * 512];
  const unsigned short* const rbase1 = &As[1][row * 512];

  const unsigned short* bq0 = BF + ((long)t0 * 128) * 512 + lane * 8;
  const unsigned short* bq1 = bq0 + 128l * 512;

  f32x4 acc0 = {0, 0, 0, 0}, acc1 = {0, 0, 0, 0};

  // prologue: stage 0 -> buf0
  {
#pragma unroll
    for (int j = 0; j < 4; ++j) {
      f32x4 lo = *(const f32x4*)(asrc + j * 128);
      f32x4 hi = *(const f32x4*)(asrc + j * 128 + 4);
      *(uint4*)(wbase0 + (((sg + 16 * j) ^ sswz) * 8)) = pack8(lo, hi);
    }
  }
  __syncthreads();

#pragma unroll 1
  for (int s = 0; s < 8; ++s) {
    // 1) issue prefetch loads for stage s+1 (8 x f32x4)
    f32x4 p0, p1, p2, p3, p4, p5, p6, p7;
    if (s + 1 < 8) {
      const float* ap = asrc + (s + 1) * 512;
      p0 = *(const f32x4*)(ap + 0 * 128); p1 = *(const f32x4*)(ap + 0 * 128 + 4);
      p2 = *(const f32x4*)(ap + 1 * 128); p3 = *(const f32x4*)(ap + 1 * 128 + 4);
      p4 = *(const f32x4*)(ap + 2 * 128); p5 = *(const f32x4*)(ap + 2 * 128 + 4);
      p6 = *(const f32x4*)(ap + 3 * 128); p7 = *(const f32x4*)(ap + 3 * 128 + 4);
    }
    // hard scheduling fence: loads above may NOT sink below this point
    __builtin_amdgcn_sched_barrier(0);

    // 2) compute stage s from buf[s&1]
    const unsigned short* rb = (s & 1) ? rbase1 : rbase0;
#pragma unroll
    for (int c = 0; c < 16; ++c) {
      s16x8 af = *(const s16x8*)(rb + (((c * 4 + quad) ^ r7) * 8));
      long kb = (long)(s * 16 + c) * 512;
      s16x8 b0 = *(const s16x8*)(bq0 + kb);
      s16x8 b1 = *(const s16x8*)(bq1 + kb);
      acc0 = __builtin_amdgcn_mfma_f32_16x16x32_bf16(af, b0, acc0, 0, 0, 0);
      acc1 = __builtin_amdgcn_mfma_f32_16x16x32_bf16(af, b1, acc1, 0, 0, 0);
    }

    // 3) pack + write stage s+1 into the other buffer
    if (s + 1 < 8) {
      unsigned short* wb = ((s + 1) & 1) ? wbase1 : wbase0;
      *(uint4*)(wb + (((sg + 0)  ^ sswz) * 8)) = pack8(p0, p1);
      *(uint4*)(wb + (((sg + 16) ^ sswz) * 8)) = pack8(p2, p3);
      *(uint4*)(wb + (((sg + 32) ^ sswz) * 8)) = pack8(p4, p5);
      *(uint4*)(wb + (((sg + 48) ^ sswz) * 8)) = pack8(p6, p7);
    }
    __syncthreads();
  }

  if constexpr (EPI == 0) {
    // fragment(n,k): n = t*16 + l16, k = mblk*32 + msub*16 + quad*4 + r
    //   kc = mblk ; (k>>3)&3 = msub*2 + (quad>>1) ; k&7 = (quad&1)*4 + r
    const int qp = msub * 2 + (quad >> 1);
    const int j0 = (quad & 1) * 4;
    long i0 = ((long)(t0 * 128 + mblk)) * 512 + (qp * 16 + l16) * 8 + j0;
    long i1 = ((long)((t0 + 1) * 128 + mblk)) * 512 + (qp * 16 + l16) * 8 + j0;
    *(ushort4*)(CF + i0) = cvt4(acc0);
    *(ushort4*)(CF + i1) = cvt4(acc1);
  } else {
    const float aLv = aLp[0], aHv = aHp[0];
    const int mr = m0 + msub * 16 + quad * 4;
    const int c0 = t0 * 16 + l16;
    const int c1 = c0 + 16;
#pragma unroll
    for (int r = 0; r < 4; ++r) {
      int rr = mr + r;
      outF[(long)rr * DD + c0] =
          aHv * acc0[r] + aLv * (Hl[(long)rr * DD + c0] + bconv[c0]);
      outF[(long)rr * DD + c1] =
          aHv * acc1[r] + aLv * (Hl[(long)rr * DD + c1] + bconv[c1]);
    }
  }
}

// ---------------------------------------------------------------------------
// launcher
// ---------------------------------------------------------------------------
extern "C" void kernel_launch(void* const* d_in, const int* in_sizes, int n_in,
                              void* d_out, int out_size, void* d_ws, size_t ws_size,
                              hipStream_t stream) {
  const float* x     = (const float*)d_in[0];
  const int*   ei    = (const int*)d_in[1];
  const float* lap   = (const float*)d_in[2];
  const float* dinv  = (const float*)d_in[3];
  const float* Wh    = (const float*)d_in[4];
  const float* Wc    = (const float*)d_in[5];
  const float* bconv = (const float*)d_in[6];
  const float* aL    = (const float*)d_in[7];
  const float* aH    = (const float*)d_in[8];
  float* out = (float*)d_out;
  char* ws = (char*)d_ws;

  int* deg        = (int*)(ws);                          // 16 KB
  int* cursor     = (int*)(ws + (16 << 10));             // 16 KB
  int* row_start  = (int*)(ws + (32 << 10));             // 16.4 KB
  int* csr        = (int*)(ws + (64 << 10));             // 512 KB
  float* dis      = (float*)(ws + (576 << 10));          // 16 KB
  unsigned short* WFh = (unsigned short*)(ws + (1l << 20));               // 128 KB
  unsigned short* WFc = (unsigned short*)(ws + (1l << 20) + (128 << 10)); // 128 KB
  unsigned short* RF  = (unsigned short*)(ws + (2l << 20));  // 2 MB fragment layout
  unsigned short* T1F = (unsigned short*)(ws + (4l << 20));  // 2 MB
  unsigned short* T2F = (unsigned short*)(ws + (6l << 20));  // 2 MB
  float* XWs = (float*)(ws + (8l << 20));                    // 4 MB
  float* Hl  = (float*)(ws + (12l << 20));                   // 4 MB

  hipMemsetAsync(ws, 0, 32 << 10, stream);   // deg + cursor

  k_prep<<<1024, 256, 0, stream>>>(ei, deg, Wh, Wc, WFh, WFc);
  k_scan<<<1, 1024, 0, stream>>>(deg, row_start, dis);
  k_scatter<<<512, 256, 0, stream>>>(ei, row_start, cursor, csr);
  k_xw<<<256, 512, 0, stream>>>(x, WFh, WFc, RF, XWs, dis);
  k_agg<<<4096, 256, 0, stream>>>(XWs, row_start, csr, dis, Hl);

  k_mm2<0><<<256, 512, 0, stream>>>(dinv, RF, T1F, nullptr, nullptr, nullptr, nullptr, nullptr);
  k_mm2<0><<<256, 512, 0, stream>>>(lap, T1F, T2F, nullptr, nullptr, nullptr, nullptr, nullptr);
  k_mm2<3><<<256, 512, 0, stream>>>(dinv, T2F, nullptr, out, Hl, bconv, aL, aH);
}